// Round 3
// baseline (843.699 us; speedup 1.0000x reference)
//
#include <hip/hip_runtime.h>
#include <math.h>

#define NN 100000
#define NE 3200000
#define OUTD 112
#define BROWS 512                 // rows per bucket (9-bit local row)
#define NBUCK 196                 // ceil(NN / BROWS)
#define FILL_CH 8192              // edges per block in hist/fill
#define FILL_B ((NE + FILL_CH - 1) / FILL_CH)   // 391
#define BLD1_T 1024               // threads for bhist/bucket_fill (16 waves)
#define SORT_T 512                // threads for csr_sort

// round-to-nearest-even fp32 -> bf16 (as raw 16 bits)
__device__ inline unsigned short f32_to_bf16(float f) {
    unsigned u = __float_as_uint(f);
    u += 0x7FFFu + ((u >> 16) & 1u);
    return (unsigned short)(u >> 16);
}
__device__ inline float bf16_bits_to_f32(unsigned b) {
    return __uint_as_float(b << 16);
}

// ---------------------------------------------------------------------------
// Kernel 1: ego = entity_embed * (1 + tanh(aux_info @ aux_W.T + aux_b))
// writes out[:,0:64] (fp32 ego, read back by layer0) + bf16 ego0h (gather).
// ---------------------------------------------------------------------------
__global__ void fuse_ego_kernel(const float* __restrict__ aux_info,
                                const float* __restrict__ entity,
                                const float* __restrict__ aux_W,
                                const float* __restrict__ aux_b,
                                unsigned short* __restrict__ ego0h,
                                float* __restrict__ out) {
    int idx = blockIdx.x * blockDim.x + threadIdx.x;
    if (idx >= NN * 64) return;
    int n = idx >> 6;
    int j = idx & 63;
    float a0 = aux_info[n * 3 + 0];
    float a1 = aux_info[n * 3 + 1];
    float a2 = aux_info[n * 3 + 2];
    float w0 = aux_W[j * 3 + 0];
    float w1 = aux_W[j * 3 + 1];
    float w2 = aux_W[j * 3 + 2];
    float t = tanhf(fmaf(a0, w0, fmaf(a1, w1, fmaf(a2, w2, aux_b[j]))));
    float e = entity[idx] * (1.0f + t);
    ego0h[idx] = f32_to_bf16(e);
    out[(size_t)n * OUTD + j] = e;
}

// ---------------------------------------------------------------------------
// CSR build, stage 1: bucket (512-row granularity) counting sort.
// ---------------------------------------------------------------------------
__global__ void bhist_kernel(const int* __restrict__ rows, int* __restrict__ gcount) {
    __shared__ int h[NBUCK];
    for (int i = threadIdx.x; i < NBUCK; i += BLD1_T) h[i] = 0;
    __syncthreads();
    int base = blockIdx.x * FILL_CH;
    int nE = NE - base; if (nE > FILL_CH) nE = FILL_CH;
    for (int i = threadIdx.x; i < nE; i += BLD1_T)
        atomicAdd(&h[rows[base + i] >> 9], 1);
    __syncthreads();
    for (int i = threadIdx.x; i < NBUCK; i += BLD1_T)
        if (h[i]) atomicAdd(&gcount[i], h[i]);
}

__global__ void bscan_kernel(const int* __restrict__ gcount,
                             int* __restrict__ bucket_base,
                             int* __restrict__ gcursor) {
    __shared__ int sh[256];
    int t = threadIdx.x;
    int v = (t < NBUCK) ? gcount[t] : 0;
    sh[t] = v;
    __syncthreads();
    for (int off = 1; off < 256; off <<= 1) {
        int u = (t >= off) ? sh[t - off] : 0;
        __syncthreads();
        sh[t] += u;
        __syncthreads();
    }
    if (t < NBUCK) {
        int excl = sh[t] - v;
        bucket_base[t] = excl;
        gcursor[t] = excl;
    }
    if (t == 255) bucket_base[NBUCK] = sh[255];
}

__global__ void bucket_fill_kernel(const int* __restrict__ rows,
                                   const int* __restrict__ cols,
                                   const float* __restrict__ vals,
                                   int* __restrict__ gcursor,
                                   int2* __restrict__ edges_b) {
    __shared__ int rowsL[FILL_CH];        // 32 KB
    __shared__ int hcnt[NBUCK];
    __shared__ int curs[NBUCK];
    int base = blockIdx.x * FILL_CH;
    int nE = NE - base; if (nE > FILL_CH) nE = FILL_CH;
    for (int i = threadIdx.x; i < NBUCK; i += BLD1_T) hcnt[i] = 0;
    __syncthreads();
    for (int i = threadIdx.x; i < nE; i += BLD1_T) {
        int r = rows[base + i];
        rowsL[i] = r;
        atomicAdd(&hcnt[r >> 9], 1);
    }
    __syncthreads();
    for (int b = threadIdx.x; b < NBUCK; b += BLD1_T) {
        int c = hcnt[b];
        curs[b] = c ? atomicAdd(&gcursor[b], c) : 0;
    }
    __syncthreads();
    for (int i = threadIdx.x; i < nE; i += BLD1_T) {
        int r = rowsL[i];
        int b = r >> 9;
        int p = atomicAdd(&curs[b], 1);
        edges_b[p] = make_int2(cols[base + i] | ((r & (BROWS - 1)) << 17),
                               __float_as_int(vals[base + i]));
    }
}

// ---------------------------------------------------------------------------
// CSR build, stage 2: within-bucket counting sort -> row-sorted PACKED edges
// (uint32 = col | bf15(val)<<17) + row_ptr.
// ---------------------------------------------------------------------------
__global__ void csr_sort_kernel(const int2* __restrict__ edges_b,
                                const int* __restrict__ bucket_base,
                                unsigned int* __restrict__ edges,
                                int* __restrict__ row_ptr) {
    __shared__ int cnt[BROWS];
    __shared__ int scn[BROWS];
    __shared__ int curs[BROWS];
    int b = blockIdx.x;
    int beg = bucket_base[b], end = bucket_base[b + 1];
    int t = threadIdx.x;
    cnt[t] = 0;
    __syncthreads();
    for (int i = beg + t; i < end; i += SORT_T)
        atomicAdd(&cnt[(edges_b[i].x >> 17) & (BROWS - 1)], 1);
    __syncthreads();
    scn[t] = cnt[t];
    __syncthreads();
    for (int off = 1; off < BROWS; off <<= 1) {
        int v = (t >= off) ? scn[t - off] : 0;
        __syncthreads();
        scn[t] += v;
        __syncthreads();
    }
    {
        int excl = scn[t] - cnt[t];
        int n = b * BROWS + t;
        if (n <= NN) row_ptr[n] = beg + excl;   // n==NN covered by last bucket
        curs[t] = beg + excl;
    }
    __syncthreads();
    for (int i = beg + t; i < end; i += SORT_T) {
        int2 e = edges_b[i];
        int rl = (e.x >> 17) & (BROWS - 1);
        int p = atomicAdd(&curs[rl], 1);
        unsigned int vb = f32_to_bf16(__int_as_float(e.y)) & 0x7FFFu;  // val>=0
        edges[p] = (unsigned int)(e.x & 0x1FFFF) | (vb << 17);
    }
}

// ---------------------------------------------------------------------------
// Pull-based segment sum, bf16 inputs, fp32 accumulate.
// L = D/2 lanes per node; each lane owns a feature PAIR (ushort2 load).
// Unroll 16 (was 8): gather is latency-bound (2.5 TB/s effective vs 6.3
// achievable, VALUBusy 48%) — double the in-flight gathers per lane.
// ---------------------------------------------------------------------------
template <int D>
__global__ void gather_kernel(const ushort2* __restrict__ egoh,
                              const unsigned int* __restrict__ edges,
                              const int* __restrict__ row_ptr,
                              float* __restrict__ side) {
    constexpr int L = D / 2;
    int n = blockIdx.x * (256 / L) + threadIdx.x / L;
    int j = threadIdx.x % L;
    if (n >= NN) return;
    int beg = row_ptr[n];
    int end = row_ptr[n + 1];
    float a0 = 0.0f, a1 = 0.0f;
    int i = beg;
    for (; i + 16 <= end; i += 16) {
        unsigned int e[16];
        ushort2 gv[16];
#pragma unroll
        for (int k = 0; k < 16; ++k) e[k] = edges[i + k];
#pragma unroll
        for (int k = 0; k < 16; ++k) gv[k] = egoh[(size_t)(e[k] & 0x1FFFFu) * L + j];
#pragma unroll
        for (int k = 0; k < 16; ++k) {
            float v = bf16_bits_to_f32(e[k] >> 17);   // sign=0
            a0 = fmaf(v, bf16_bits_to_f32(gv[k].x), a0);
            a1 = fmaf(v, bf16_bits_to_f32(gv[k].y), a1);
        }
    }
    for (; i + 8 <= end; i += 8) {
        unsigned int e[8];
        ushort2 gv[8];
#pragma unroll
        for (int k = 0; k < 8; ++k) e[k] = edges[i + k];
#pragma unroll
        for (int k = 0; k < 8; ++k) gv[k] = egoh[(size_t)(e[k] & 0x1FFFFu) * L + j];
#pragma unroll
        for (int k = 0; k < 8; ++k) {
            float v = bf16_bits_to_f32(e[k] >> 17);
            a0 = fmaf(v, bf16_bits_to_f32(gv[k].x), a0);
            a1 = fmaf(v, bf16_bits_to_f32(gv[k].y), a1);
        }
    }
    for (; i < end; ++i) {
        unsigned int e = edges[i];
        ushort2 g = egoh[(size_t)(e & 0x1FFFFu) * L + j];
        float v = bf16_bits_to_f32(e >> 17);
        a0 = fmaf(v, bf16_bits_to_f32(g.x), a0);
        a1 = fmaf(v, bf16_bits_to_f32(g.y), a1);
    }
    side[(size_t)n * D + 2 * j]     = a0;
    side[(size_t)n * D + 2 * j + 1] = a1;
}

// ---------------------------------------------------------------------------
// Bi-interaction layer + l2norm. RESTRUCTURED (old: 61 us, LDS-issue bound:
// ~80 DS instr/node, scalar b32 W reads re-issued per node).
//   - Each thread computes output j for NPT nodes -> W float4 loaded ONCE per
//     thread per k-group from GLOBAL (8-16 KB table, L1/L2-resident) and
//     reused across NPT nodes. W leaves the LDS entirely.
//   - s=ego+side, p=ego*side hoisted into staging (computed once per node,
//     not once per (node,j)); stored as LDS rows, read back as BROADCAST
//     ds_read_b128 (2 unique addrs/wave -> conflict-free, near-free).
//   - DS instr/node: ~80 -> ~17. fp32 fmaf chain, k-ascending: accumulation
//     order IDENTICAL to the old kernel -> bit-identical results.
// ---------------------------------------------------------------------------
template <int DIN, int DOUT, int NB>
__global__ __launch_bounds__(256) void layer_kernel(
    const float* __restrict__ ego, int ego_stride,
    const float* __restrict__ side,
    const float* __restrict__ W1, const float* __restrict__ b1,
    const float* __restrict__ W2, const float* __restrict__ b2,
    float* __restrict__ ego_next,            // nullable
    unsigned short* __restrict__ ego_next_h, // nullable
    float* __restrict__ out, int out_off)
{
    constexpr int RW  = DIN + 4;             // pad: rows 16B-aligned, banks spread
    constexpr int CH  = DIN / 4;             // float4 chunks per node
    constexpr int NPT = NB * DOUT / 256;     // nodes per thread (8 for L0, 4 for L1)
    static_assert(NB * DOUT % 256 == 0, "");

    __shared__ float sArr[NB][RW];
    __shared__ float pArr[NB][RW];

    const int node0 = blockIdx.x * NB;

    // ---- staging: s/p hoist, coalesced float4 in, b128 out ----
    for (int i = threadIdx.x; i < NB * CH; i += 256) {
        int m = i / CH;
        int c = i - m * CH;
        int n = node0 + m;
        if (n < NN) {
            float4 e  = *(const float4*)&ego[(size_t)n * ego_stride + c * 4];
            float4 sd = *(const float4*)&side[(size_t)n * DIN + c * 4];
            *(float4*)&sArr[m][c * 4] =
                make_float4(e.x + sd.x, e.y + sd.y, e.z + sd.z, e.w + sd.w);
            *(float4*)&pArr[m][c * 4] =
                make_float4(e.x * sd.x, e.y * sd.y, e.z * sd.z, e.w * sd.w);
        }
    }
    __syncthreads();

    // ---- transform: thread (j, slot) does output j for nodes slot*NPT.. ----
    const int j    = threadIdx.x % DOUT;
    const int slot = threadIdx.x / DOUT;

    float acc1[NPT], acc2[NPT];
    float bb1 = b1[j], bb2 = b2[j];
#pragma unroll
    for (int m8 = 0; m8 < NPT; ++m8) { acc1[m8] = bb1; acc2[m8] = bb2; }

#pragma unroll
    for (int kg = 0; kg < CH; ++kg) {
        float4 w1 = *(const float4*)&W1[j * DIN + kg * 4];   // L1/L2-hot
        float4 w2 = *(const float4*)&W2[j * DIN + kg * 4];
#pragma unroll
        for (int m8 = 0; m8 < NPT; ++m8) {
            int m = slot * NPT + m8;
            float4 sv = *(const float4*)&sArr[m][kg * 4];    // broadcast b128
            float4 pv = *(const float4*)&pArr[m][kg * 4];
            acc1[m8] = fmaf(sv.x, w1.x, acc1[m8]);
            acc1[m8] = fmaf(sv.y, w1.y, acc1[m8]);
            acc1[m8] = fmaf(sv.z, w1.z, acc1[m8]);
            acc1[m8] = fmaf(sv.w, w1.w, acc1[m8]);
            acc2[m8] = fmaf(pv.x, w2.x, acc2[m8]);
            acc2[m8] = fmaf(pv.y, w2.y, acc2[m8]);
            acc2[m8] = fmaf(pv.z, w2.z, acc2[m8]);
            acc2[m8] = fmaf(pv.w, w2.w, acc2[m8]);
        }
    }

    // ---- epilogue: leaky, v, l2norm (width-DOUT shuffle within node group) ----
#pragma unroll
    for (int m8 = 0; m8 < NPT; ++m8) {
        int n = node0 + slot * NPT + m8;
        float s  = acc1[m8]; s  = (s  > 0.0f) ? s  : 0.01f * s;
        float bb = acc2[m8]; bb = (bb > 0.0f) ? bb : 0.01f * bb;
        float v = s + bb;
        float sq = v * v;
#pragma unroll
        for (int off = DOUT / 2; off > 0; off >>= 1)
            sq += __shfl_xor(sq, off, DOUT);
        float norm = sqrtf(sq);
        norm = (norm > 1e-12f) ? norm : 1e-12f;
        if (n < NN) {
            if (ego_next)   ego_next[(size_t)n * DOUT + j] = v;
            if (ego_next_h) ego_next_h[(size_t)n * DOUT + j] = f32_to_bf16(v);
            out[(size_t)n * OUTD + out_off + j] = v / norm;
        }
    }
}

// ---------------------------------------------------------------------------
extern "C" void kernel_launch(void* const* d_in, const int* in_sizes, int n_in,
                              void* d_out, int out_size, void* d_ws, size_t ws_size,
                              hipStream_t stream) {
    const float* aux_info  = (const float*)d_in[0];
    const float* entity    = (const float*)d_in[1];
    const float* aux_W     = (const float*)d_in[2];
    const float* aux_b     = (const float*)d_in[3];
    const float* edge_vals = (const float*)d_in[4];
    const int*   edge_rows = (const int*)d_in[5];
    const int*   edge_cols = (const int*)d_in[6];
    const float* W1_0 = (const float*)d_in[7];
    const float* b1_0 = (const float*)d_in[8];
    const float* W2_0 = (const float*)d_in[9];
    const float* b2_0 = (const float*)d_in[10];
    const float* W1_1 = (const float*)d_in[11];
    const float* b1_1 = (const float*)d_in[12];
    const float* W2_1 = (const float*)d_in[13];
    const float* b2_1 = (const float*)d_in[14];
    float* out = (float*)d_out;

    // workspace layout (4-byte words). Aliases:
    //   edges_b (stage-1, dead after csr_sort)  <->  side0 (written by gather64)
    //   ego0h (dead after gather64)             <->  ego1h (written by layer0)
    float* region0 = (float*)d_ws;
    int2*  edges_b = (int2*)region0;                       // 6.4M words
    float* side0   = region0;                              // alias
    unsigned short* ego0h = (unsigned short*)(region0 + (size_t)NE * 2); // 3.2M words
    unsigned short* ego1h = ego0h;                         // alias (1.6M words)
    unsigned int* edges = (unsigned int*)((float*)ego0h + (size_t)NN * 32); // 3.2M words
    float* ego1  = (float*)(edges + NE);                   // 3.2M words
    float* side1 = ego1 + (size_t)NN * 32;                 // 3.2M words
    int* row_ptr     = (int*)(side1 + (size_t)NN * 32);
    int* bucket_base = row_ptr + NN + 1;
    int* gcount      = bucket_base + NBUCK + 1;            // reused as cursor

    // --- CSR build (graph shared by both layers) ---
    hipMemsetAsync(gcount, 0, (size_t)NBUCK * sizeof(int), stream);
    bhist_kernel<<<FILL_B, BLD1_T, 0, stream>>>(edge_rows, gcount);
    bscan_kernel<<<1, 256, 0, stream>>>(gcount, bucket_base, gcount);
    bucket_fill_kernel<<<FILL_B, BLD1_T, 0, stream>>>(
        edge_rows, edge_cols, edge_vals, gcount, edges_b);
    csr_sort_kernel<<<NBUCK, SORT_T, 0, stream>>>(edges_b, bucket_base, edges, row_ptr);

    // --- 1) holographic fusion -> out[:,0:64] (fp32 ego) + bf16 ego0h ---
    {
        int total = NN * 64;
        fuse_ego_kernel<<<(total + 255) / 256, 256, 0, stream>>>(
            aux_info, entity, aux_W, aux_b, ego0h, out);
    }
    // --- 2) layer 0 segment-sum (pull, bf16) ---
    gather_kernel<64><<<(NN + 7) / 8, 256, 0, stream>>>(
        (const ushort2*)ego0h, edges, row_ptr, side0);
    // --- 3) layer 0 transform (ego read from out[:,0:64]) -> ego1 (+bf16) ---
    layer_kernel<64, 32, 64><<<(NN + 63) / 64, 256, 0, stream>>>(
        out, OUTD, side0, W1_0, b1_0, W2_0, b2_0, ego1, ego1h, out, 64);
    // --- 4) layer 1 segment-sum (pull, bf16) ---
    gather_kernel<32><<<(NN + 15) / 16, 256, 0, stream>>>(
        (const ushort2*)ego1h, edges, row_ptr, side1);
    // --- 5) layer 1 transform -> out[:,96:112] ---
    layer_kernel<32, 16, 64><<<(NN + 63) / 64, 256, 0, stream>>>(
        ego1, 32, side1, W1_1, b1_1, W2_1, b2_1, nullptr, nullptr, out, 96);
}

// Round 4
// 418.029 us; speedup vs baseline: 2.0183x; 2.0183x over previous
//
#include <hip/hip_runtime.h>
#include <math.h>

#define NN 100000
#define NE 3200000
#define OUTD 112
#define BROWS 512                 // rows per bucket (9-bit local row)
#define NBUCK 196                 // ceil(NN / BROWS)
#define FILL_CH 8192              // edges per block in hist/fill
#define FILL_B ((NE + FILL_CH - 1) / FILL_CH)   // 391
#define BLD1_T 1024               // threads for bhist/bucket_fill (16 waves)
#define SORT_T 512                // threads for csr_sort

// round-to-nearest-even fp32 -> bf16 (as raw 16 bits)
__device__ inline unsigned short f32_to_bf16(float f) {
    unsigned u = __float_as_uint(f);
    u += 0x7FFFu + ((u >> 16) & 1u);
    return (unsigned short)(u >> 16);
}
__device__ inline float bf16_bits_to_f32(unsigned b) {
    return __uint_as_float(b << 16);
}

// ---------------------------------------------------------------------------
// Kernel 1: ego = entity_embed * (1 + tanh(aux_info @ aux_W.T + aux_b))
// writes out[:,0:64] (fp32 ego, read back by layer0) + bf16 ego0h (gather).
// ---------------------------------------------------------------------------
__global__ void fuse_ego_kernel(const float* __restrict__ aux_info,
                                const float* __restrict__ entity,
                                const float* __restrict__ aux_W,
                                const float* __restrict__ aux_b,
                                unsigned short* __restrict__ ego0h,
                                float* __restrict__ out) {
    int idx = blockIdx.x * blockDim.x + threadIdx.x;
    if (idx >= NN * 64) return;
    int n = idx >> 6;
    int j = idx & 63;
    float a0 = aux_info[n * 3 + 0];
    float a1 = aux_info[n * 3 + 1];
    float a2 = aux_info[n * 3 + 2];
    float w0 = aux_W[j * 3 + 0];
    float w1 = aux_W[j * 3 + 1];
    float w2 = aux_W[j * 3 + 2];
    float t = tanhf(fmaf(a0, w0, fmaf(a1, w1, fmaf(a2, w2, aux_b[j]))));
    float e = entity[idx] * (1.0f + t);
    ego0h[idx] = f32_to_bf16(e);
    out[(size_t)n * OUTD + j] = e;
}

// ---------------------------------------------------------------------------
// CSR build, stage 1: bucket (512-row granularity) counting sort.
// ---------------------------------------------------------------------------
__global__ void bhist_kernel(const int* __restrict__ rows, int* __restrict__ gcount) {
    __shared__ int h[NBUCK];
    for (int i = threadIdx.x; i < NBUCK; i += BLD1_T) h[i] = 0;
    __syncthreads();
    int base = blockIdx.x * FILL_CH;
    int nE = NE - base; if (nE > FILL_CH) nE = FILL_CH;
    for (int i = threadIdx.x; i < nE; i += BLD1_T)
        atomicAdd(&h[rows[base + i] >> 9], 1);
    __syncthreads();
    for (int i = threadIdx.x; i < NBUCK; i += BLD1_T)
        if (h[i]) atomicAdd(&gcount[i], h[i]);
}

__global__ void bscan_kernel(const int* __restrict__ gcount,
                             int* __restrict__ bucket_base,
                             int* __restrict__ gcursor) {
    __shared__ int sh[256];
    int t = threadIdx.x;
    int v = (t < NBUCK) ? gcount[t] : 0;
    sh[t] = v;
    __syncthreads();
    for (int off = 1; off < 256; off <<= 1) {
        int u = (t >= off) ? sh[t - off] : 0;
        __syncthreads();
        sh[t] += u;
        __syncthreads();
    }
    if (t < NBUCK) {
        int excl = sh[t] - v;
        bucket_base[t] = excl;
        gcursor[t] = excl;
    }
    if (t == 255) bucket_base[NBUCK] = sh[255];
}

__global__ void bucket_fill_kernel(const int* __restrict__ rows,
                                   const int* __restrict__ cols,
                                   const float* __restrict__ vals,
                                   int* __restrict__ gcursor,
                                   int2* __restrict__ edges_b) {
    __shared__ int rowsL[FILL_CH];        // 32 KB
    __shared__ int hcnt[NBUCK];
    __shared__ int curs[NBUCK];
    int base = blockIdx.x * FILL_CH;
    int nE = NE - base; if (nE > FILL_CH) nE = FILL_CH;
    for (int i = threadIdx.x; i < NBUCK; i += BLD1_T) hcnt[i] = 0;
    __syncthreads();
    for (int i = threadIdx.x; i < nE; i += BLD1_T) {
        int r = rows[base + i];
        rowsL[i] = r;
        atomicAdd(&hcnt[r >> 9], 1);
    }
    __syncthreads();
    for (int b = threadIdx.x; b < NBUCK; b += BLD1_T) {
        int c = hcnt[b];
        curs[b] = c ? atomicAdd(&gcursor[b], c) : 0;
    }
    __syncthreads();
    for (int i = threadIdx.x; i < nE; i += BLD1_T) {
        int r = rowsL[i];
        int b = r >> 9;
        int p = atomicAdd(&curs[b], 1);
        edges_b[p] = make_int2(cols[base + i] | ((r & (BROWS - 1)) << 17),
                               __float_as_int(vals[base + i]));
    }
}

// ---------------------------------------------------------------------------
// CSR build, stage 2: within-bucket counting sort -> row-sorted PACKED edges
// (uint32 = col | bf15(val)<<17) + row_ptr.
// ---------------------------------------------------------------------------
__global__ void csr_sort_kernel(const int2* __restrict__ edges_b,
                                const int* __restrict__ bucket_base,
                                unsigned int* __restrict__ edges,
                                int* __restrict__ row_ptr) {
    __shared__ int cnt[BROWS];
    __shared__ int scn[BROWS];
    __shared__ int curs[BROWS];
    int b = blockIdx.x;
    int beg = bucket_base[b], end = bucket_base[b + 1];
    int t = threadIdx.x;
    cnt[t] = 0;
    __syncthreads();
    for (int i = beg + t; i < end; i += SORT_T)
        atomicAdd(&cnt[(edges_b[i].x >> 17) & (BROWS - 1)], 1);
    __syncthreads();
    scn[t] = cnt[t];
    __syncthreads();
    for (int off = 1; off < BROWS; off <<= 1) {
        int v = (t >= off) ? scn[t - off] : 0;
        __syncthreads();
        scn[t] += v;
        __syncthreads();
    }
    {
        int excl = scn[t] - cnt[t];
        int n = b * BROWS + t;
        if (n <= NN) row_ptr[n] = beg + excl;   // n==NN covered by last bucket
        curs[t] = beg + excl;
    }
    __syncthreads();
    for (int i = beg + t; i < end; i += SORT_T) {
        int2 e = edges_b[i];
        int rl = (e.x >> 17) & (BROWS - 1);
        int p = atomicAdd(&curs[rl], 1);
        unsigned int vb = f32_to_bf16(__int_as_float(e.y)) & 0x7FFFu;  // val>=0
        edges[p] = (unsigned int)(e.x & 0x1FFFF) | (vb << 17);
    }
}

// ---------------------------------------------------------------------------
// Pull-based segment sum, bf16 inputs, fp32 accumulate.
// L = D/2 lanes per node; each lane owns a feature PAIR (ushort2 load).
// Unroll 16: gather is latency-bound — keep 16 in-flight gathers per lane.
// ---------------------------------------------------------------------------
template <int D>
__global__ void gather_kernel(const ushort2* __restrict__ egoh,
                              const unsigned int* __restrict__ edges,
                              const int* __restrict__ row_ptr,
                              float* __restrict__ side) {
    constexpr int L = D / 2;
    int n = blockIdx.x * (256 / L) + threadIdx.x / L;
    int j = threadIdx.x % L;
    if (n >= NN) return;
    int beg = row_ptr[n];
    int end = row_ptr[n + 1];
    float a0 = 0.0f, a1 = 0.0f;
    int i = beg;
    for (; i + 16 <= end; i += 16) {
        unsigned int e[16];
        ushort2 gv[16];
#pragma unroll
        for (int k = 0; k < 16; ++k) e[k] = edges[i + k];
#pragma unroll
        for (int k = 0; k < 16; ++k) gv[k] = egoh[(size_t)(e[k] & 0x1FFFFu) * L + j];
#pragma unroll
        for (int k = 0; k < 16; ++k) {
            float v = bf16_bits_to_f32(e[k] >> 17);   // sign=0
            a0 = fmaf(v, bf16_bits_to_f32(gv[k].x), a0);
            a1 = fmaf(v, bf16_bits_to_f32(gv[k].y), a1);
        }
    }
    for (; i + 8 <= end; i += 8) {
        unsigned int e[8];
        ushort2 gv[8];
#pragma unroll
        for (int k = 0; k < 8; ++k) e[k] = edges[i + k];
#pragma unroll
        for (int k = 0; k < 8; ++k) gv[k] = egoh[(size_t)(e[k] & 0x1FFFFu) * L + j];
#pragma unroll
        for (int k = 0; k < 8; ++k) {
            float v = bf16_bits_to_f32(e[k] >> 17);
            a0 = fmaf(v, bf16_bits_to_f32(gv[k].x), a0);
            a1 = fmaf(v, bf16_bits_to_f32(gv[k].y), a1);
        }
    }
    for (; i < end; ++i) {
        unsigned int e = edges[i];
        ushort2 g = egoh[(size_t)(e & 0x1FFFFu) * L + j];
        float v = bf16_bits_to_f32(e >> 17);
        a0 = fmaf(v, bf16_bits_to_f32(g.x), a0);
        a1 = fmaf(v, bf16_bits_to_f32(g.y), a1);
    }
    side[(size_t)n * D + 2 * j]     = a0;
    side[(size_t)n * D + 2 * j + 1] = a1;
}

// ---------------------------------------------------------------------------
// Bi-interaction layer + l2norm. v2 of the multi-node restructure.
// R3's version spilled (VGPR=256, 884 MB scratch writes): full kg-unroll
// with NPT=8 hoisted 32 W float4 loads (128 regs) + pipelined LDS reads.
// Fixes, register-budgeted explicitly:
//   - NPT=4 (acc = 8 VGPR)
//   - #pragma unroll 2 on kg loop: <=2 iterations' W loads live (16 VGPR),
//     kills the hoist-everything pathology, keeps load/FMA overlap
//   - __launch_bounds__(256,4): allocator capped at 128 VGPR, 16 waves/CU
// Structure (unchanged from v1): thread owns output j for NPT nodes; W read
// per kg as global float4 (8-16 KB table, L1-resident row walk) reused
// across NPT nodes; s=ego+side, p=ego*side hoisted into staging (once per
// node); s/p read back as 2-unique-addr ds_read_b128 (conflict-free).
// DS model: 128 b128/wave per 8 nodes ~ 192 cyc/node -> ~31 us for layer0.
// fp32 fmaf, k-ascending: accumulation order identical -> same absmax.
// ---------------------------------------------------------------------------
template <int DIN, int DOUT, int NB>
__global__ __launch_bounds__(256, 4) void layer_kernel(
    const float* __restrict__ ego, int ego_stride,
    const float* __restrict__ side,
    const float* __restrict__ W1, const float* __restrict__ b1,
    const float* __restrict__ W2, const float* __restrict__ b2,
    float* __restrict__ ego_next,            // nullable
    unsigned short* __restrict__ ego_next_h, // nullable
    float* __restrict__ out, int out_off)
{
    constexpr int RW  = DIN + 4;             // pad: rows 16B-aligned, banks spread
    constexpr int CH  = DIN / 4;             // float4 chunks per node
    constexpr int NPT = NB * DOUT / 256;     // nodes per thread (4 for both layers)
    static_assert(NB * DOUT % 256 == 0, "");
    static_assert(NPT == 4, "register budget tuned for NPT=4");

    __shared__ float sArr[NB][RW];
    __shared__ float pArr[NB][RW];

    const int node0 = blockIdx.x * NB;

    // ---- staging: s/p hoist, coalesced float4 in, b128 out ----
    for (int i = threadIdx.x; i < NB * CH; i += 256) {
        int m = i / CH;
        int c = i - m * CH;
        int n = node0 + m;
        if (n < NN) {
            float4 e  = *(const float4*)&ego[(size_t)n * ego_stride + c * 4];
            float4 sd = *(const float4*)&side[(size_t)n * DIN + c * 4];
            *(float4*)&sArr[m][c * 4] =
                make_float4(e.x + sd.x, e.y + sd.y, e.z + sd.z, e.w + sd.w);
            *(float4*)&pArr[m][c * 4] =
                make_float4(e.x * sd.x, e.y * sd.y, e.z * sd.z, e.w * sd.w);
        }
    }
    __syncthreads();

    // ---- transform: thread (j, slot) does output j for nodes slot*NPT.. ----
    const int j     = threadIdx.x % DOUT;
    const int slot  = threadIdx.x / DOUT;
    const int mbase = slot * NPT;

    float acc1[NPT], acc2[NPT];
    {
        float bb1 = b1[j], bb2 = b2[j];
#pragma unroll
        for (int m8 = 0; m8 < NPT; ++m8) { acc1[m8] = bb1; acc2[m8] = bb2; }
    }

    const float4* W1v = (const float4*)(W1 + j * DIN);   // L1-hot row walk
    const float4* W2v = (const float4*)(W2 + j * DIN);

#pragma unroll 2
    for (int kg = 0; kg < CH; ++kg) {
        float4 w1 = W1v[kg];
        float4 w2 = W2v[kg];
#pragma unroll
        for (int m8 = 0; m8 < NPT; ++m8) {
            float4 sv = *(const float4*)&sArr[mbase + m8][kg * 4]; // 2-addr b128
            float4 pv = *(const float4*)&pArr[mbase + m8][kg * 4];
            acc1[m8] = fmaf(sv.x, w1.x, acc1[m8]);
            acc1[m8] = fmaf(sv.y, w1.y, acc1[m8]);
            acc1[m8] = fmaf(sv.z, w1.z, acc1[m8]);
            acc1[m8] = fmaf(sv.w, w1.w, acc1[m8]);
            acc2[m8] = fmaf(pv.x, w2.x, acc2[m8]);
            acc2[m8] = fmaf(pv.y, w2.y, acc2[m8]);
            acc2[m8] = fmaf(pv.z, w2.z, acc2[m8]);
            acc2[m8] = fmaf(pv.w, w2.w, acc2[m8]);
        }
    }

    // ---- epilogue: leaky, v, l2norm (width-DOUT shuffle within node group) ----
#pragma unroll
    for (int m8 = 0; m8 < NPT; ++m8) {
        int n = node0 + mbase + m8;
        float s  = acc1[m8]; s  = (s  > 0.0f) ? s  : 0.01f * s;
        float bb = acc2[m8]; bb = (bb > 0.0f) ? bb : 0.01f * bb;
        float v = s + bb;
        float sq = v * v;
#pragma unroll
        for (int off = DOUT / 2; off > 0; off >>= 1)
            sq += __shfl_xor(sq, off, DOUT);
        float norm = sqrtf(sq);
        norm = (norm > 1e-12f) ? norm : 1e-12f;
        if (n < NN) {
            if (ego_next)   ego_next[(size_t)n * DOUT + j] = v;
            if (ego_next_h) ego_next_h[(size_t)n * DOUT + j] = f32_to_bf16(v);
            out[(size_t)n * OUTD + out_off + j] = v / norm;
        }
    }
}

// ---------------------------------------------------------------------------
extern "C" void kernel_launch(void* const* d_in, const int* in_sizes, int n_in,
                              void* d_out, int out_size, void* d_ws, size_t ws_size,
                              hipStream_t stream) {
    const float* aux_info  = (const float*)d_in[0];
    const float* entity    = (const float*)d_in[1];
    const float* aux_W     = (const float*)d_in[2];
    const float* aux_b     = (const float*)d_in[3];
    const float* edge_vals = (const float*)d_in[4];
    const int*   edge_rows = (const int*)d_in[5];
    const int*   edge_cols = (const int*)d_in[6];
    const float* W1_0 = (const float*)d_in[7];
    const float* b1_0 = (const float*)d_in[8];
    const float* W2_0 = (const float*)d_in[9];
    const float* b2_0 = (const float*)d_in[10];
    const float* W1_1 = (const float*)d_in[11];
    const float* b1_1 = (const float*)d_in[12];
    const float* W2_1 = (const float*)d_in[13];
    const float* b2_1 = (const float*)d_in[14];
    float* out = (float*)d_out;

    // workspace layout (4-byte words). Aliases:
    //   edges_b (stage-1, dead after csr_sort)  <->  side0 (written by gather64)
    //   ego0h (dead after gather64)             <->  ego1h (written by layer0)
    float* region0 = (float*)d_ws;
    int2*  edges_b = (int2*)region0;                       // 6.4M words
    float* side0   = region0;                              // alias
    unsigned short* ego0h = (unsigned short*)(region0 + (size_t)NE * 2); // 3.2M words
    unsigned short* ego1h = ego0h;                         // alias (1.6M words)
    unsigned int* edges = (unsigned int*)((float*)ego0h + (size_t)NN * 32); // 3.2M words
    float* ego1  = (float*)(edges + NE);                   // 3.2M words
    float* side1 = ego1 + (size_t)NN * 32;                 // 3.2M words
    int* row_ptr     = (int*)(side1 + (size_t)NN * 32);
    int* bucket_base = row_ptr + NN + 1;
    int* gcount      = bucket_base + NBUCK + 1;            // reused as cursor

    // --- CSR build (graph shared by both layers) ---
    hipMemsetAsync(gcount, 0, (size_t)NBUCK * sizeof(int), stream);
    bhist_kernel<<<FILL_B, BLD1_T, 0, stream>>>(edge_rows, gcount);
    bscan_kernel<<<1, 256, 0, stream>>>(gcount, bucket_base, gcount);
    bucket_fill_kernel<<<FILL_B, BLD1_T, 0, stream>>>(
        edge_rows, edge_cols, edge_vals, gcount, edges_b);
    csr_sort_kernel<<<NBUCK, SORT_T, 0, stream>>>(edges_b, bucket_base, edges, row_ptr);

    // --- 1) holographic fusion -> out[:,0:64] (fp32 ego) + bf16 ego0h ---
    {
        int total = NN * 64;
        fuse_ego_kernel<<<(total + 255) / 256, 256, 0, stream>>>(
            aux_info, entity, aux_W, aux_b, ego0h, out);
    }
    // --- 2) layer 0 segment-sum (pull, bf16) ---
    gather_kernel<64><<<(NN + 7) / 8, 256, 0, stream>>>(
        (const ushort2*)ego0h, edges, row_ptr, side0);
    // --- 3) layer 0 transform (ego read from out[:,0:64]) -> ego1 (+bf16) ---
    layer_kernel<64, 32, 32><<<(NN + 31) / 32, 256, 0, stream>>>(
        out, OUTD, side0, W1_0, b1_0, W2_0, b2_0, ego1, ego1h, out, 64);
    // --- 4) layer 1 segment-sum (pull, bf16) ---
    gather_kernel<32><<<(NN + 15) / 16, 256, 0, stream>>>(
        (const ushort2*)ego1h, edges, row_ptr, side1);
    // --- 5) layer 1 transform -> out[:,96:112] ---
    layer_kernel<32, 16, 64><<<(NN + 63) / 64, 256, 0, stream>>>(
        ego1, 32, side1, W1_1, b1_1, W2_1, b2_1, nullptr, nullptr, out, 96);
}

// Round 5
// 398.214 us; speedup vs baseline: 2.1187x; 1.0498x over previous
//
#include <hip/hip_runtime.h>
#include <math.h>

#define NN 100000
#define NE 3200000
#define OUTD 112
#define BROWS 512                 // rows per bucket (9-bit local row)
#define NBUCK 196                 // ceil(NN / BROWS)
#define FILL_CH 8192              // edges per block in hist/fill
#define FILL_B ((NE + FILL_CH - 1) / FILL_CH)   // 391
#define BLD1_T 1024               // threads for bhist/bucket_fill (16 waves)
#define SORT_T 512                // threads for csr_sort

// round-to-nearest-even fp32 -> bf16 (as raw 16 bits)
__device__ inline unsigned short f32_to_bf16(float f) {
    unsigned u = __float_as_uint(f);
    u += 0x7FFFu + ((u >> 16) & 1u);
    return (unsigned short)(u >> 16);
}
__device__ inline float bf16_bits_to_f32(unsigned b) {
    return __uint_as_float(b << 16);
}

// ---------------------------------------------------------------------------
// Kernel 1: ego = entity_embed * (1 + tanh(aux_info @ aux_W.T + aux_b))
// writes out[:,0:64] (fp32 ego, read back by layer0) + bf16 ego0h (gather).
// ---------------------------------------------------------------------------
__global__ void fuse_ego_kernel(const float* __restrict__ aux_info,
                                const float* __restrict__ entity,
                                const float* __restrict__ aux_W,
                                const float* __restrict__ aux_b,
                                unsigned short* __restrict__ ego0h,
                                float* __restrict__ out) {
    int idx = blockIdx.x * blockDim.x + threadIdx.x;
    if (idx >= NN * 64) return;
    int n = idx >> 6;
    int j = idx & 63;
    float a0 = aux_info[n * 3 + 0];
    float a1 = aux_info[n * 3 + 1];
    float a2 = aux_info[n * 3 + 2];
    float w0 = aux_W[j * 3 + 0];
    float w1 = aux_W[j * 3 + 1];
    float w2 = aux_W[j * 3 + 2];
    float t = tanhf(fmaf(a0, w0, fmaf(a1, w1, fmaf(a2, w2, aux_b[j]))));
    float e = entity[idx] * (1.0f + t);
    ego0h[idx] = f32_to_bf16(e);
    out[(size_t)n * OUTD + j] = e;
}

// ---------------------------------------------------------------------------
// CSR build, stage 1: bucket (512-row granularity) counting sort.
// ---------------------------------------------------------------------------
__global__ void bhist_kernel(const int* __restrict__ rows, int* __restrict__ gcount) {
    __shared__ int h[NBUCK];
    for (int i = threadIdx.x; i < NBUCK; i += BLD1_T) h[i] = 0;
    __syncthreads();
    int base = blockIdx.x * FILL_CH;
    int nE = NE - base; if (nE > FILL_CH) nE = FILL_CH;
    for (int i = threadIdx.x; i < nE; i += BLD1_T)
        atomicAdd(&h[rows[base + i] >> 9], 1);
    __syncthreads();
    for (int i = threadIdx.x; i < NBUCK; i += BLD1_T)
        if (h[i]) atomicAdd(&gcount[i], h[i]);
}

__global__ void bscan_kernel(const int* __restrict__ gcount,
                             int* __restrict__ bucket_base,
                             int* __restrict__ gcursor) {
    __shared__ int sh[256];
    int t = threadIdx.x;
    int v = (t < NBUCK) ? gcount[t] : 0;
    sh[t] = v;
    __syncthreads();
    for (int off = 1; off < 256; off <<= 1) {
        int u = (t >= off) ? sh[t - off] : 0;
        __syncthreads();
        sh[t] += u;
        __syncthreads();
    }
    if (t < NBUCK) {
        int excl = sh[t] - v;
        bucket_base[t] = excl;
        gcursor[t] = excl;
    }
    if (t == 255) bucket_base[NBUCK] = sh[255];
}

__global__ void bucket_fill_kernel(const int* __restrict__ rows,
                                   const int* __restrict__ cols,
                                   const float* __restrict__ vals,
                                   int* __restrict__ gcursor,
                                   int2* __restrict__ edges_b) {
    __shared__ int rowsL[FILL_CH];        // 32 KB
    __shared__ int hcnt[NBUCK];
    __shared__ int curs[NBUCK];
    int base = blockIdx.x * FILL_CH;
    int nE = NE - base; if (nE > FILL_CH) nE = FILL_CH;
    for (int i = threadIdx.x; i < NBUCK; i += BLD1_T) hcnt[i] = 0;
    __syncthreads();
    for (int i = threadIdx.x; i < nE; i += BLD1_T) {
        int r = rows[base + i];
        rowsL[i] = r;
        atomicAdd(&hcnt[r >> 9], 1);
    }
    __syncthreads();
    for (int b = threadIdx.x; b < NBUCK; b += BLD1_T) {
        int c = hcnt[b];
        curs[b] = c ? atomicAdd(&gcursor[b], c) : 0;
    }
    __syncthreads();
    for (int i = threadIdx.x; i < nE; i += BLD1_T) {
        int r = rowsL[i];
        int b = r >> 9;
        int p = atomicAdd(&curs[b], 1);
        edges_b[p] = make_int2(cols[base + i] | ((r & (BROWS - 1)) << 17),
                               __float_as_int(vals[base + i]));
    }
}

// ---------------------------------------------------------------------------
// CSR build, stage 2: within-bucket counting sort -> row-sorted PACKED edges
// (uint32 = col | bf15(val)<<17) + row_ptr.
// ---------------------------------------------------------------------------
__global__ void csr_sort_kernel(const int2* __restrict__ edges_b,
                                const int* __restrict__ bucket_base,
                                unsigned int* __restrict__ edges,
                                int* __restrict__ row_ptr) {
    __shared__ int cnt[BROWS];
    __shared__ int scn[BROWS];
    __shared__ int curs[BROWS];
    int b = blockIdx.x;
    int beg = bucket_base[b], end = bucket_base[b + 1];
    int t = threadIdx.x;
    cnt[t] = 0;
    __syncthreads();
    for (int i = beg + t; i < end; i += SORT_T)
        atomicAdd(&cnt[(edges_b[i].x >> 17) & (BROWS - 1)], 1);
    __syncthreads();
    scn[t] = cnt[t];
    __syncthreads();
    for (int off = 1; off < BROWS; off <<= 1) {
        int v = (t >= off) ? scn[t - off] : 0;
        __syncthreads();
        scn[t] += v;
        __syncthreads();
    }
    {
        int excl = scn[t] - cnt[t];
        int n = b * BROWS + t;
        if (n <= NN) row_ptr[n] = beg + excl;   // n==NN covered by last bucket
        curs[t] = beg + excl;
    }
    __syncthreads();
    for (int i = beg + t; i < end; i += SORT_T) {
        int2 e = edges_b[i];
        int rl = (e.x >> 17) & (BROWS - 1);
        int p = atomicAdd(&curs[rl], 1);
        unsigned int vb = f32_to_bf16(__int_as_float(e.y)) & 0x7FFFu;  // val>=0
        edges[p] = (unsigned int)(e.x & 0x1FFFF) | (vb << 17);
    }
}

// ---------------------------------------------------------------------------
// Pull-based segment sum, bf16 inputs, fp32 accumulate.
// L = D/2 lanes per node; each lane owns a feature PAIR (ushort2 load).
// Unroll 16: gather is latency-bound — keep 16 in-flight gathers per lane.
// ---------------------------------------------------------------------------
template <int D>
__global__ void gather_kernel(const ushort2* __restrict__ egoh,
                              const unsigned int* __restrict__ edges,
                              const int* __restrict__ row_ptr,
                              float* __restrict__ side) {
    constexpr int L = D / 2;
    int n = blockIdx.x * (256 / L) + threadIdx.x / L;
    int j = threadIdx.x % L;
    if (n >= NN) return;
    int beg = row_ptr[n];
    int end = row_ptr[n + 1];
    float a0 = 0.0f, a1 = 0.0f;
    int i = beg;
    for (; i + 16 <= end; i += 16) {
        unsigned int e[16];
        ushort2 gv[16];
#pragma unroll
        for (int k = 0; k < 16; ++k) e[k] = edges[i + k];
#pragma unroll
        for (int k = 0; k < 16; ++k) gv[k] = egoh[(size_t)(e[k] & 0x1FFFFu) * L + j];
#pragma unroll
        for (int k = 0; k < 16; ++k) {
            float v = bf16_bits_to_f32(e[k] >> 17);   // sign=0
            a0 = fmaf(v, bf16_bits_to_f32(gv[k].x), a0);
            a1 = fmaf(v, bf16_bits_to_f32(gv[k].y), a1);
        }
    }
    for (; i + 8 <= end; i += 8) {
        unsigned int e[8];
        ushort2 gv[8];
#pragma unroll
        for (int k = 0; k < 8; ++k) e[k] = edges[i + k];
#pragma unroll
        for (int k = 0; k < 8; ++k) gv[k] = egoh[(size_t)(e[k] & 0x1FFFFu) * L + j];
#pragma unroll
        for (int k = 0; k < 8; ++k) {
            float v = bf16_bits_to_f32(e[k] >> 17);
            a0 = fmaf(v, bf16_bits_to_f32(gv[k].x), a0);
            a1 = fmaf(v, bf16_bits_to_f32(gv[k].y), a1);
        }
    }
    for (; i < end; ++i) {
        unsigned int e = edges[i];
        ushort2 g = egoh[(size_t)(e & 0x1FFFFu) * L + j];
        float v = bf16_bits_to_f32(e >> 17);
        a0 = fmaf(v, bf16_bits_to_f32(g.x), a0);
        a1 = fmaf(v, bf16_bits_to_f32(g.y), a1);
    }
    side[(size_t)n * D + 2 * j]     = a0;
    side[(size_t)n * D + 2 * j + 1] = a1;
}

// ---------------------------------------------------------------------------
// Bi-interaction layer + l2norm. v3.
// History: R0 = 61us (W in LDS, scalar reads RE-ISSUED per node, DS-issue
// bound). R3 = spill (full unroll, NPT=8). R4 = 65us (W from GLOBAL per kg:
// latency-bound, VALUBusy 33%).
// v3 = R0's W-in-LDS (short, hideable latency) + R4's multi-node reuse
// (NPT=4) + b128 W reads (2 instr/kg instead of 8 scalars):
//   - W staged once as float4 quads W1q[kg][j]: thread's read W1q[kg*DOUT+j]
//     is one ds_read_b128, reused across 4 nodes (R0 re-read W per node).
//   - s=ego+side, p=ego*side hoisted at staging (once per node, not per j);
//     read back as 2-distinct-addr broadcast ds_read_b128; sArr row stride
//     DIN+4 floats keeps paired slots on disjoint bank quads.
//   - DS model/wave(8 nodes)/kg: 2 W b128 + 8 s/p b128 = 10 instr; x16 kg
//     = 160 b128/wave -> ~30-40us layer0 (vs 65).
//   - unroll 2: <=2 iterations' LDS loads live; no hoist-spill pathology.
// fp32 fmaf, k-ascending: accumulation order identical -> same absmax.
// ---------------------------------------------------------------------------
template <int DIN, int DOUT, int NB>
__global__ __launch_bounds__(256, 4) void layer_kernel(
    const float* __restrict__ ego, int ego_stride,
    const float* __restrict__ side,
    const float* __restrict__ W1, const float* __restrict__ b1,
    const float* __restrict__ W2, const float* __restrict__ b2,
    float* __restrict__ ego_next,            // nullable
    unsigned short* __restrict__ ego_next_h, // nullable
    float* __restrict__ out, int out_off)
{
    constexpr int RW  = DIN + 4;             // row stride: 16B-aligned, bank-spread
    constexpr int CH  = DIN / 4;             // float4 chunks per node
    constexpr int NPT = NB * DOUT / 256;     // nodes per thread
    static_assert(NB * DOUT % 256 == 0, "");
    static_assert(NPT == 4, "register budget tuned for NPT=4");

    __shared__ float sArr[NB][RW];
    __shared__ float pArr[NB][RW];
    __shared__ float4 W1q[CH * DOUT];        // quad (j, k=kg*4..+3) at [kg*DOUT+j]
    __shared__ float4 W2q[CH * DOUT];

    const int node0 = blockIdx.x * NB;

    // ---- W staging: coalesced float4 global read -> LDS quads ----
    for (int t = threadIdx.x; t < CH * DOUT; t += 256) {
        int j  = t / CH;
        int kg = t - j * CH;
        W1q[kg * DOUT + j] = *(const float4*)&W1[j * DIN + kg * 4];
        W2q[kg * DOUT + j] = *(const float4*)&W2[j * DIN + kg * 4];
    }

    // ---- s/p staging: hoisted s=e+sd, p=e*sd; coalesced float4 in ----
    for (int i = threadIdx.x; i < NB * CH; i += 256) {
        int m = i / CH;
        int c = i - m * CH;
        int n = node0 + m;
        if (n < NN) {
            float4 e  = *(const float4*)&ego[(size_t)n * ego_stride + c * 4];
            float4 sd = *(const float4*)&side[(size_t)n * DIN + c * 4];
            *(float4*)&sArr[m][c * 4] =
                make_float4(e.x + sd.x, e.y + sd.y, e.z + sd.z, e.w + sd.w);
            *(float4*)&pArr[m][c * 4] =
                make_float4(e.x * sd.x, e.y * sd.y, e.z * sd.z, e.w * sd.w);
        }
    }
    __syncthreads();

    // ---- transform: thread (j, slot) does output j for nodes slot*NPT.. ----
    const int j     = threadIdx.x % DOUT;
    const int slot  = threadIdx.x / DOUT;
    const int mbase = slot * NPT;

    float acc1[NPT], acc2[NPT];
    {
        float bb1 = b1[j], bb2 = b2[j];
#pragma unroll
        for (int m8 = 0; m8 < NPT; ++m8) { acc1[m8] = bb1; acc2[m8] = bb2; }
    }

#pragma unroll 2
    for (int kg = 0; kg < CH; ++kg) {
        float4 w1 = W1q[kg * DOUT + j];      // b128, reused across NPT nodes
        float4 w2 = W2q[kg * DOUT + j];
#pragma unroll
        for (int m8 = 0; m8 < NPT; ++m8) {
            float4 sv = *(const float4*)&sArr[mbase + m8][kg * 4]; // broadcast b128
            float4 pv = *(const float4*)&pArr[mbase + m8][kg * 4];
            acc1[m8] = fmaf(sv.x, w1.x, acc1[m8]);
            acc1[m8] = fmaf(sv.y, w1.y, acc1[m8]);
            acc1[m8] = fmaf(sv.z, w1.z, acc1[m8]);
            acc1[m8] = fmaf(sv.w, w1.w, acc1[m8]);
            acc2[m8] = fmaf(pv.x, w2.x, acc2[m8]);
            acc2[m8] = fmaf(pv.y, w2.y, acc2[m8]);
            acc2[m8] = fmaf(pv.z, w2.z, acc2[m8]);
            acc2[m8] = fmaf(pv.w, w2.w, acc2[m8]);
        }
    }

    // ---- epilogue: leaky, v, l2norm (width-DOUT shuffle within node group) ----
#pragma unroll
    for (int m8 = 0; m8 < NPT; ++m8) {
        int n = node0 + mbase + m8;
        float s  = acc1[m8]; s  = (s  > 0.0f) ? s  : 0.01f * s;
        float bb = acc2[m8]; bb = (bb > 0.0f) ? bb : 0.01f * bb;
        float v = s + bb;
        float sq = v * v;
#pragma unroll
        for (int off = DOUT / 2; off > 0; off >>= 1)
            sq += __shfl_xor(sq, off, DOUT);
        float norm = sqrtf(sq);
        norm = (norm > 1e-12f) ? norm : 1e-12f;
        if (n < NN) {
            if (ego_next)   ego_next[(size_t)n * DOUT + j] = v;
            if (ego_next_h) ego_next_h[(size_t)n * DOUT + j] = f32_to_bf16(v);
            out[(size_t)n * OUTD + out_off + j] = v / norm;
        }
    }
}

// ---------------------------------------------------------------------------
extern "C" void kernel_launch(void* const* d_in, const int* in_sizes, int n_in,
                              void* d_out, int out_size, void* d_ws, size_t ws_size,
                              hipStream_t stream) {
    const float* aux_info  = (const float*)d_in[0];
    const float* entity    = (const float*)d_in[1];
    const float* aux_W     = (const float*)d_in[2];
    const float* aux_b     = (const float*)d_in[3];
    const float* edge_vals = (const float*)d_in[4];
    const int*   edge_rows = (const int*)d_in[5];
    const int*   edge_cols = (const int*)d_in[6];
    const float* W1_0 = (const float*)d_in[7];
    const float* b1_0 = (const float*)d_in[8];
    const float* W2_0 = (const float*)d_in[9];
    const float* b2_0 = (const float*)d_in[10];
    const float* W1_1 = (const float*)d_in[11];
    const float* b1_1 = (const float*)d_in[12];
    const float* W2_1 = (const float*)d_in[13];
    const float* b2_1 = (const float*)d_in[14];
    float* out = (float*)d_out;

    // workspace layout (4-byte words). Aliases:
    //   edges_b (stage-1, dead after csr_sort)  <->  side0 (written by gather64)
    //   ego0h (dead after gather64)             <->  ego1h (written by layer0)
    float* region0 = (float*)d_ws;
    int2*  edges_b = (int2*)region0;                       // 6.4M words
    float* side0   = region0;                              // alias
    unsigned short* ego0h = (unsigned short*)(region0 + (size_t)NE * 2); // 3.2M words
    unsigned short* ego1h = ego0h;                         // alias (1.6M words)
    unsigned int* edges = (unsigned int*)((float*)ego0h + (size_t)NN * 32); // 3.2M words
    float* ego1  = (float*)(edges + NE);                   // 3.2M words
    float* side1 = ego1 + (size_t)NN * 32;                 // 3.2M words
    int* row_ptr     = (int*)(side1 + (size_t)NN * 32);
    int* bucket_base = row_ptr + NN + 1;
    int* gcount      = bucket_base + NBUCK + 1;            // reused as cursor

    // --- CSR build (graph shared by both layers) ---
    hipMemsetAsync(gcount, 0, (size_t)NBUCK * sizeof(int), stream);
    bhist_kernel<<<FILL_B, BLD1_T, 0, stream>>>(edge_rows, gcount);
    bscan_kernel<<<1, 256, 0, stream>>>(gcount, bucket_base, gcount);
    bucket_fill_kernel<<<FILL_B, BLD1_T, 0, stream>>>(
        edge_rows, edge_cols, edge_vals, gcount, edges_b);
    csr_sort_kernel<<<NBUCK, SORT_T, 0, stream>>>(edges_b, bucket_base, edges, row_ptr);

    // --- 1) holographic fusion -> out[:,0:64] (fp32 ego) + bf16 ego0h ---
    {
        int total = NN * 64;
        fuse_ego_kernel<<<(total + 255) / 256, 256, 0, stream>>>(
            aux_info, entity, aux_W, aux_b, ego0h, out);
    }
    // --- 2) layer 0 segment-sum (pull, bf16) ---
    gather_kernel<64><<<(NN + 7) / 8, 256, 0, stream>>>(
        (const ushort2*)ego0h, edges, row_ptr, side0);
    // --- 3) layer 0 transform (ego read from out[:,0:64]) -> ego1 (+bf16) ---
    layer_kernel<64, 32, 32><<<(NN + 31) / 32, 256, 0, stream>>>(
        out, OUTD, side0, W1_0, b1_0, W2_0, b2_0, ego1, ego1h, out, 64);
    // --- 4) layer 1 segment-sum (pull, bf16) ---
    gather_kernel<32><<<(NN + 15) / 16, 256, 0, stream>>>(
        (const ushort2*)ego1h, edges, row_ptr, side1);
    // --- 5) layer 1 transform -> out[:,96:112] ---
    layer_kernel<32, 16, 64><<<(NN + 63) / 64, 256, 0, stream>>>(
        ego1, 32, side1, W1_1, b1_1, W2_1, b2_1, nullptr, nullptr, out, 96);
}

// Round 6
// 385.135 us; speedup vs baseline: 2.1907x; 1.0340x over previous
//
#include <hip/hip_runtime.h>
#include <math.h>

#define NN 100000
#define NE 3200000
#define OUTD 112
#define BROWS 512                 // rows per bucket (9-bit local row)
#define NBUCK 196                 // ceil(NN / BROWS)
#define FILL_CH 8192              // edges per block in hist/fill
#define FILL_B ((NE + FILL_CH - 1) / FILL_CH)   // 391
#define BLD1_T 1024               // threads for bhist/bucket_fill (16 waves)
#define SORT_T 512                // threads for csr_sort

// round-to-nearest-even fp32 -> bf16 (as raw 16 bits)
__device__ inline unsigned short f32_to_bf16(float f) {
    unsigned u = __float_as_uint(f);
    u += 0x7FFFu + ((u >> 16) & 1u);
    return (unsigned short)(u >> 16);
}
__device__ inline float bf16_bits_to_f32(unsigned b) {
    return __uint_as_float(b << 16);
}

// ---------------------------------------------------------------------------
// Kernel 1: ego = entity_embed * (1 + tanh(aux_info @ aux_W.T + aux_b))
// writes out[:,0:64] (fp32 ego, read back by layer0) + bf16 ego0h (gather).
// ---------------------------------------------------------------------------
__global__ void fuse_ego_kernel(const float* __restrict__ aux_info,
                                const float* __restrict__ entity,
                                const float* __restrict__ aux_W,
                                const float* __restrict__ aux_b,
                                unsigned short* __restrict__ ego0h,
                                float* __restrict__ out) {
    int idx = blockIdx.x * blockDim.x + threadIdx.x;
    if (idx >= NN * 64) return;
    int n = idx >> 6;
    int j = idx & 63;
    float a0 = aux_info[n * 3 + 0];
    float a1 = aux_info[n * 3 + 1];
    float a2 = aux_info[n * 3 + 2];
    float w0 = aux_W[j * 3 + 0];
    float w1 = aux_W[j * 3 + 1];
    float w2 = aux_W[j * 3 + 2];
    float t = tanhf(fmaf(a0, w0, fmaf(a1, w1, fmaf(a2, w2, aux_b[j]))));
    float e = entity[idx] * (1.0f + t);
    ego0h[idx] = f32_to_bf16(e);
    out[(size_t)n * OUTD + j] = e;
}

// ---------------------------------------------------------------------------
// CSR build, stage 1: bucket (512-row granularity) counting sort.
// ---------------------------------------------------------------------------
__global__ void bhist_kernel(const int* __restrict__ rows, int* __restrict__ gcount) {
    __shared__ int h[NBUCK];
    for (int i = threadIdx.x; i < NBUCK; i += BLD1_T) h[i] = 0;
    __syncthreads();
    int base = blockIdx.x * FILL_CH;
    int nE = NE - base; if (nE > FILL_CH) nE = FILL_CH;
    for (int i = threadIdx.x; i < nE; i += BLD1_T)
        atomicAdd(&h[rows[base + i] >> 9], 1);
    __syncthreads();
    for (int i = threadIdx.x; i < NBUCK; i += BLD1_T)
        if (h[i]) atomicAdd(&gcount[i], h[i]);
}

__global__ void bscan_kernel(const int* __restrict__ gcount,
                             int* __restrict__ bucket_base,
                             int* __restrict__ gcursor) {
    __shared__ int sh[256];
    int t = threadIdx.x;
    int v = (t < NBUCK) ? gcount[t] : 0;
    sh[t] = v;
    __syncthreads();
    for (int off = 1; off < 256; off <<= 1) {
        int u = (t >= off) ? sh[t - off] : 0;
        __syncthreads();
        sh[t] += u;
        __syncthreads();
    }
    if (t < NBUCK) {
        int excl = sh[t] - v;
        bucket_base[t] = excl;
        gcursor[t] = excl;
    }
    if (t == 255) bucket_base[NBUCK] = sh[255];
}

__global__ void bucket_fill_kernel(const int* __restrict__ rows,
                                   const int* __restrict__ cols,
                                   const float* __restrict__ vals,
                                   int* __restrict__ gcursor,
                                   int2* __restrict__ edges_b) {
    __shared__ int rowsL[FILL_CH];        // 32 KB
    __shared__ int hcnt[NBUCK];
    __shared__ int curs[NBUCK];
    int base = blockIdx.x * FILL_CH;
    int nE = NE - base; if (nE > FILL_CH) nE = FILL_CH;
    for (int i = threadIdx.x; i < NBUCK; i += BLD1_T) hcnt[i] = 0;
    __syncthreads();
    for (int i = threadIdx.x; i < nE; i += BLD1_T) {
        int r = rows[base + i];
        rowsL[i] = r;
        atomicAdd(&hcnt[r >> 9], 1);
    }
    __syncthreads();
    for (int b = threadIdx.x; b < NBUCK; b += BLD1_T) {
        int c = hcnt[b];
        curs[b] = c ? atomicAdd(&gcursor[b], c) : 0;
    }
    __syncthreads();
    for (int i = threadIdx.x; i < nE; i += BLD1_T) {
        int r = rowsL[i];
        int b = r >> 9;
        int p = atomicAdd(&curs[b], 1);
        edges_b[p] = make_int2(cols[base + i] | ((r & (BROWS - 1)) << 17),
                               __float_as_int(vals[base + i]));
    }
}

// ---------------------------------------------------------------------------
// CSR build, stage 2: within-bucket counting sort -> row-sorted PACKED edges
// (uint32 = col | bf15(val)<<17) + row_ptr.
// ---------------------------------------------------------------------------
__global__ void csr_sort_kernel(const int2* __restrict__ edges_b,
                                const int* __restrict__ bucket_base,
                                unsigned int* __restrict__ edges,
                                int* __restrict__ row_ptr) {
    __shared__ int cnt[BROWS];
    __shared__ int scn[BROWS];
    __shared__ int curs[BROWS];
    int b = blockIdx.x;
    int beg = bucket_base[b], end = bucket_base[b + 1];
    int t = threadIdx.x;
    cnt[t] = 0;
    __syncthreads();
    for (int i = beg + t; i < end; i += SORT_T)
        atomicAdd(&cnt[(edges_b[i].x >> 17) & (BROWS - 1)], 1);
    __syncthreads();
    scn[t] = cnt[t];
    __syncthreads();
    for (int off = 1; off < BROWS; off <<= 1) {
        int v = (t >= off) ? scn[t - off] : 0;
        __syncthreads();
        scn[t] += v;
        __syncthreads();
    }
    {
        int excl = scn[t] - cnt[t];
        int n = b * BROWS + t;
        if (n <= NN) row_ptr[n] = beg + excl;   // n==NN covered by last bucket
        curs[t] = beg + excl;
    }
    __syncthreads();
    for (int i = beg + t; i < end; i += SORT_T) {
        int2 e = edges_b[i];
        int rl = (e.x >> 17) & (BROWS - 1);
        int p = atomicAdd(&curs[rl], 1);
        unsigned int vb = f32_to_bf16(__int_as_float(e.y)) & 0x7FFFu;  // val>=0
        edges[p] = (unsigned int)(e.x & 0x1FFFF) | (vb << 17);
    }
}

// ---------------------------------------------------------------------------
// Pull-based segment sum, v2: 16-BYTE gathers.
// Old version (ushort2, L=32): one gather instr per 2 edges + one broadcast
// edge load per 2 edges = ~3.2M VMEM wave-instrs, each costing ~16 TA cycles
// of address processing + 4-5 VALU of 64-bit addr calc -> VMEM-issue bound
// (60us, VALUBusy 52%, HBM 48%, LDS idle).
// v2: 32 lanes/node split (es, fo) = (edge-sublane, feature-octet), FO=D/8.
// Each lane gathers uint4 = 8 bf16 features; 8 lanes cover a row; one gather
// instr covers 8 edges -> 4x fewer VMEM instrs, 4x fewer redundant edge
// loads/converts. bf16 decode: <<16 / &0xFFFF0000 (1 instr/feature).
// Per-lane partials over es-strided edges; 2-3 round __shfl_xor butterfly at
// the end (tree-sum reassociation, same class as the CSR edge reorder).
// ---------------------------------------------------------------------------
template <int D>
__global__ __launch_bounds__(256) void gather_kernel(
    const uint4* __restrict__ egoh4,   // row = FO uint4 (128B for D=64)
    const unsigned int* __restrict__ edges,
    const int* __restrict__ row_ptr,
    float* __restrict__ side) {
    constexpr int FO = D / 8;          // uint4 per row  (8 for D=64, 4 for D=32)
    constexpr int ES = 32 / FO;        // edges per step (4 for D=64, 8 for D=32)
    constexpr int U  = 16 / ES;        // steps unrolled -> 16 edges per iter
    const int gt = blockIdx.x * 256 + threadIdx.x;
    const int n  = gt >> 5;            // 32 lanes per node, 2 nodes per wave
    const int li = gt & 31;
    const int es = li / FO;
    const int fo = li % FO;
    if (n >= NN) return;
    int beg = row_ptr[n];
    int end = row_ptr[n + 1];
    float a[8] = {0.f, 0.f, 0.f, 0.f, 0.f, 0.f, 0.f, 0.f};
    int i = beg;
    for (; i + U * ES <= end; i += U * ES) {
        unsigned ew[U];
        uint4 g[U];
#pragma unroll
        for (int u = 0; u < U; ++u) ew[u] = edges[i + u * ES + es];
#pragma unroll
        for (int u = 0; u < U; ++u)
            g[u] = egoh4[(size_t)(ew[u] & 0x1FFFFu) * FO + fo];
#pragma unroll
        for (int u = 0; u < U; ++u) {
            float v = __uint_as_float((ew[u] >> 1) & 0xFFFF0000u);  // bf15 val
            a[0] = fmaf(v, __uint_as_float(g[u].x << 16), a[0]);
            a[1] = fmaf(v, __uint_as_float(g[u].x & 0xFFFF0000u), a[1]);
            a[2] = fmaf(v, __uint_as_float(g[u].y << 16), a[2]);
            a[3] = fmaf(v, __uint_as_float(g[u].y & 0xFFFF0000u), a[3]);
            a[4] = fmaf(v, __uint_as_float(g[u].z << 16), a[4]);
            a[5] = fmaf(v, __uint_as_float(g[u].z & 0xFFFF0000u), a[5]);
            a[6] = fmaf(v, __uint_as_float(g[u].w << 16), a[6]);
            a[7] = fmaf(v, __uint_as_float(g[u].w & 0xFFFF0000u), a[7]);
        }
    }
    for (; i + ES <= end; i += ES) {
        unsigned ew = edges[i + es];
        uint4 g = egoh4[(size_t)(ew & 0x1FFFFu) * FO + fo];
        float v = __uint_as_float((ew >> 1) & 0xFFFF0000u);
        a[0] = fmaf(v, __uint_as_float(g.x << 16), a[0]);
        a[1] = fmaf(v, __uint_as_float(g.x & 0xFFFF0000u), a[1]);
        a[2] = fmaf(v, __uint_as_float(g.y << 16), a[2]);
        a[3] = fmaf(v, __uint_as_float(g.y & 0xFFFF0000u), a[3]);
        a[4] = fmaf(v, __uint_as_float(g.z << 16), a[4]);
        a[5] = fmaf(v, __uint_as_float(g.z & 0xFFFF0000u), a[5]);
        a[6] = fmaf(v, __uint_as_float(g.w << 16), a[6]);
        a[7] = fmaf(v, __uint_as_float(g.w & 0xFFFF0000u), a[7]);
    }
    if (i + es < end) {                 // tail: < ES edges, predicated
        unsigned ew = edges[i + es];
        uint4 g = egoh4[(size_t)(ew & 0x1FFFFu) * FO + fo];
        float v = __uint_as_float((ew >> 1) & 0xFFFF0000u);
        a[0] = fmaf(v, __uint_as_float(g.x << 16), a[0]);
        a[1] = fmaf(v, __uint_as_float(g.x & 0xFFFF0000u), a[1]);
        a[2] = fmaf(v, __uint_as_float(g.y << 16), a[2]);
        a[3] = fmaf(v, __uint_as_float(g.y & 0xFFFF0000u), a[3]);
        a[4] = fmaf(v, __uint_as_float(g.z << 16), a[4]);
        a[5] = fmaf(v, __uint_as_float(g.z & 0xFFFF0000u), a[5]);
        a[6] = fmaf(v, __uint_as_float(g.w << 16), a[6]);
        a[7] = fmaf(v, __uint_as_float(g.w & 0xFFFF0000u), a[7]);
    }
    // butterfly-reduce across es lanes (stride FO..16, within 32-lane group)
#pragma unroll
    for (int st = FO; st < 32; st <<= 1) {
#pragma unroll
        for (int q = 0; q < 8; ++q) a[q] += __shfl_xor(a[q], st);
    }
    if (es == 0)
        *(float4*)&side[(size_t)n * D + fo * 8] =
            make_float4(a[0], a[1], a[2], a[3]);
    else if (es == 1)
        *(float4*)&side[(size_t)n * D + fo * 8 + 4] =
            make_float4(a[4], a[5], a[6], a[7]);
}

// ---------------------------------------------------------------------------
// Bi-interaction layer + l2norm. v3 (R5: works, <59us for layer0).
// W staged once as float4 quads in LDS (b128 read, reused across NPT=4
// nodes); s=ego+side, p=ego*side hoisted at staging; broadcast b128 reads;
// unroll 2 keeps register pressure low (VGPR 28, no spill).
// fp32 fmaf, k-ascending: same accumulation order as baseline.
// ---------------------------------------------------------------------------
template <int DIN, int DOUT, int NB>
__global__ __launch_bounds__(256, 4) void layer_kernel(
    const float* __restrict__ ego, int ego_stride,
    const float* __restrict__ side,
    const float* __restrict__ W1, const float* __restrict__ b1,
    const float* __restrict__ W2, const float* __restrict__ b2,
    float* __restrict__ ego_next,            // nullable
    unsigned short* __restrict__ ego_next_h, // nullable
    float* __restrict__ out, int out_off)
{
    constexpr int RW  = DIN + 4;             // row stride: 16B-aligned, bank-spread
    constexpr int CH  = DIN / 4;             // float4 chunks per node
    constexpr int NPT = NB * DOUT / 256;     // nodes per thread
    static_assert(NB * DOUT % 256 == 0, "");
    static_assert(NPT == 4, "register budget tuned for NPT=4");

    __shared__ float sArr[NB][RW];
    __shared__ float pArr[NB][RW];
    __shared__ float4 W1q[CH * DOUT];        // quad (j, k=kg*4..+3) at [kg*DOUT+j]
    __shared__ float4 W2q[CH * DOUT];

    const int node0 = blockIdx.x * NB;

    // ---- W staging: coalesced float4 global read -> LDS quads ----
    for (int t = threadIdx.x; t < CH * DOUT; t += 256) {
        int j  = t / CH;
        int kg = t - j * CH;
        W1q[kg * DOUT + j] = *(const float4*)&W1[j * DIN + kg * 4];
        W2q[kg * DOUT + j] = *(const float4*)&W2[j * DIN + kg * 4];
    }

    // ---- s/p staging: hoisted s=e+sd, p=e*sd; coalesced float4 in ----
    for (int i = threadIdx.x; i < NB * CH; i += 256) {
        int m = i / CH;
        int c = i - m * CH;
        int n = node0 + m;
        if (n < NN) {
            float4 e  = *(const float4*)&ego[(size_t)n * ego_stride + c * 4];
            float4 sd = *(const float4*)&side[(size_t)n * DIN + c * 4];
            *(float4*)&sArr[m][c * 4] =
                make_float4(e.x + sd.x, e.y + sd.y, e.z + sd.z, e.w + sd.w);
            *(float4*)&pArr[m][c * 4] =
                make_float4(e.x * sd.x, e.y * sd.y, e.z * sd.z, e.w * sd.w);
        }
    }
    __syncthreads();

    // ---- transform: thread (j, slot) does output j for nodes slot*NPT.. ----
    const int j     = threadIdx.x % DOUT;
    const int slot  = threadIdx.x / DOUT;
    const int mbase = slot * NPT;

    float acc1[NPT], acc2[NPT];
    {
        float bb1 = b1[j], bb2 = b2[j];
#pragma unroll
        for (int m8 = 0; m8 < NPT; ++m8) { acc1[m8] = bb1; acc2[m8] = bb2; }
    }

#pragma unroll 2
    for (int kg = 0; kg < CH; ++kg) {
        float4 w1 = W1q[kg * DOUT + j];      // b128, reused across NPT nodes
        float4 w2 = W2q[kg * DOUT + j];
#pragma unroll
        for (int m8 = 0; m8 < NPT; ++m8) {
            float4 sv = *(const float4*)&sArr[mbase + m8][kg * 4]; // broadcast b128
            float4 pv = *(const float4*)&pArr[mbase + m8][kg * 4];
            acc1[m8] = fmaf(sv.x, w1.x, acc1[m8]);
            acc1[m8] = fmaf(sv.y, w1.y, acc1[m8]);
            acc1[m8] = fmaf(sv.z, w1.z, acc1[m8]);
            acc1[m8] = fmaf(sv.w, w1.w, acc1[m8]);
            acc2[m8] = fmaf(pv.x, w2.x, acc2[m8]);
            acc2[m8] = fmaf(pv.y, w2.y, acc2[m8]);
            acc2[m8] = fmaf(pv.z, w2.z, acc2[m8]);
            acc2[m8] = fmaf(pv.w, w2.w, acc2[m8]);
        }
    }

    // ---- epilogue: leaky, v, l2norm (width-DOUT shuffle within node group) ----
#pragma unroll
    for (int m8 = 0; m8 < NPT; ++m8) {
        int n = node0 + mbase + m8;
        float s  = acc1[m8]; s  = (s  > 0.0f) ? s  : 0.01f * s;
        float bb = acc2[m8]; bb = (bb > 0.0f) ? bb : 0.01f * bb;
        float v = s + bb;
        float sq = v * v;
#pragma unroll
        for (int off = DOUT / 2; off > 0; off >>= 1)
            sq += __shfl_xor(sq, off, DOUT);
        float norm = sqrtf(sq);
        norm = (norm > 1e-12f) ? norm : 1e-12f;
        if (n < NN) {
            if (ego_next)   ego_next[(size_t)n * DOUT + j] = v;
            if (ego_next_h) ego_next_h[(size_t)n * DOUT + j] = f32_to_bf16(v);
            out[(size_t)n * OUTD + out_off + j] = v / norm;
        }
    }
}

// ---------------------------------------------------------------------------
extern "C" void kernel_launch(void* const* d_in, const int* in_sizes, int n_in,
                              void* d_out, int out_size, void* d_ws, size_t ws_size,
                              hipStream_t stream) {
    const float* aux_info  = (const float*)d_in[0];
    const float* entity    = (const float*)d_in[1];
    const float* aux_W     = (const float*)d_in[2];
    const float* aux_b     = (const float*)d_in[3];
    const float* edge_vals = (const float*)d_in[4];
    const int*   edge_rows = (const int*)d_in[5];
    const int*   edge_cols = (const int*)d_in[6];
    const float* W1_0 = (const float*)d_in[7];
    const float* b1_0 = (const float*)d_in[8];
    const float* W2_0 = (const float*)d_in[9];
    const float* b2_0 = (const float*)d_in[10];
    const float* W1_1 = (const float*)d_in[11];
    const float* b1_1 = (const float*)d_in[12];
    const float* W2_1 = (const float*)d_in[13];
    const float* b2_1 = (const float*)d_in[14];
    float* out = (float*)d_out;

    // workspace layout (4-byte words). Aliases:
    //   edges_b (stage-1, dead after csr_sort)  <->  side0 (written by gather64)
    //   ego0h (dead after gather64)             <->  ego1h (written by layer0)
    float* region0 = (float*)d_ws;
    int2*  edges_b = (int2*)region0;                       // 6.4M words
    float* side0   = region0;                              // alias
    unsigned short* ego0h = (unsigned short*)(region0 + (size_t)NE * 2); // 3.2M words
    unsigned short* ego1h = ego0h;                         // alias (1.6M words)
    unsigned int* edges = (unsigned int*)((float*)ego0h + (size_t)NN * 32); // 3.2M words
    float* ego1  = (float*)(edges + NE);                   // 3.2M words
    float* side1 = ego1 + (size_t)NN * 32;                 // 3.2M words
    int* row_ptr     = (int*)(side1 + (size_t)NN * 32);
    int* bucket_base = row_ptr + NN + 1;
    int* gcount      = bucket_base + NBUCK + 1;            // reused as cursor

    // --- CSR build (graph shared by both layers) ---
    hipMemsetAsync(gcount, 0, (size_t)NBUCK * sizeof(int), stream);
    bhist_kernel<<<FILL_B, BLD1_T, 0, stream>>>(edge_rows, gcount);
    bscan_kernel<<<1, 256, 0, stream>>>(gcount, bucket_base, gcount);
    bucket_fill_kernel<<<FILL_B, BLD1_T, 0, stream>>>(
        edge_rows, edge_cols, edge_vals, gcount, edges_b);
    csr_sort_kernel<<<NBUCK, SORT_T, 0, stream>>>(edges_b, bucket_base, edges, row_ptr);

    // --- 1) holographic fusion -> out[:,0:64] (fp32 ego) + bf16 ego0h ---
    {
        int total = NN * 64;
        fuse_ego_kernel<<<(total + 255) / 256, 256, 0, stream>>>(
            aux_info, entity, aux_W, aux_b, ego0h, out);
    }
    // --- 2) layer 0 segment-sum (pull, bf16, 16B gathers) ---
    gather_kernel<64><<<NN / 8, 256, 0, stream>>>(
        (const uint4*)ego0h, edges, row_ptr, side0);
    // --- 3) layer 0 transform (ego read from out[:,0:64]) -> ego1 (+bf16) ---
    layer_kernel<64, 32, 32><<<(NN + 31) / 32, 256, 0, stream>>>(
        out, OUTD, side0, W1_0, b1_0, W2_0, b2_0, ego1, ego1h, out, 64);
    // --- 4) layer 1 segment-sum (pull, bf16, 16B gathers) ---
    gather_kernel<32><<<NN / 8, 256, 0, stream>>>(
        (const uint4*)ego1h, edges, row_ptr, side1);
    // --- 5) layer 1 transform -> out[:,96:112] ---
    layer_kernel<32, 16, 64><<<(NN + 63) / 64, 256, 0, stream>>>(
        ego1, 32, side1, W1_1, b1_1, W2_1, b2_1, nullptr, nullptr, out, 96);
}